// Round 1
// baseline (918.200 us; speedup 1.0000x reference)
//
#include <hip/hip_runtime.h>
#include <math.h>

#define NN 100000
#define NE 1600000
#define ET (NE + NN)

// ---------------- CSR build ----------------
__global__ __launch_bounds__(256) void k_hist(const int* __restrict__ dst, int* __restrict__ counts) {
  int i = blockIdx.x * 256 + threadIdx.x;
  if (i < NE) atomicAdd(&counts[dst[i]], 1);
  else if (i < ET) atomicAdd(&counts[i - NE], 1);   // self loop for node i-NE
}

__global__ __launch_bounds__(256) void k_scan1(const int* __restrict__ counts, int* __restrict__ partial,
                                               int* __restrict__ blksum) {
  __shared__ int lds[256];
  int b = blockIdx.x, t = threadIdx.x;
  int base = b * 1024 + t * 4;
  int v[4];
#pragma unroll
  for (int j = 0; j < 4; j++) v[j] = (base + j < NN) ? counts[base + j] : 0;
  int s = 0;
#pragma unroll
  for (int j = 0; j < 4; j++) { s += v[j]; v[j] = s; }   // inclusive within thread
  lds[t] = s; __syncthreads();
  int tot = s;
  for (int off = 1; off < 256; off <<= 1) {
    int u = 0; if (t >= off) u = lds[t - off];
    __syncthreads(); lds[t] += u; __syncthreads();
  }
  int pre = lds[t] - tot;
#pragma unroll
  for (int j = 0; j < 4; j++) if (base + j < NN) partial[base + j] = pre + v[j];
  if (t == 255) blksum[b] = lds[255];
}

__global__ __launch_bounds__(256) void k_scan2(int* __restrict__ blksum, int nb) {
  __shared__ int lds[256];
  int t = threadIdx.x;
  int v = (t < nb) ? blksum[t] : 0;
  lds[t] = v; __syncthreads();
  for (int off = 1; off < 256; off <<= 1) {
    int u = 0; if (t >= off) u = lds[t - off];
    __syncthreads(); lds[t] += u; __syncthreads();
  }
  if (t < nb) blksum[t] = lds[t] - v;   // exclusive block offsets
}

__global__ __launch_bounds__(256) void k_scan3(const int* __restrict__ partial, const int* __restrict__ blksum,
                                               const int* __restrict__ counts, int* __restrict__ rowptr,
                                               int* __restrict__ cursor) {
  int i = blockIdx.x * 256 + threadIdx.x;
  if (i >= NN) return;
  int incl = partial[i] + blksum[i >> 10];
  rowptr[i + 1] = incl;
  cursor[i] = incl - counts[i];
  if (i == 0) rowptr[0] = 0;
}

__global__ __launch_bounds__(256) void k_scatter(const int* __restrict__ src, const int* __restrict__ dst,
                                                 int* __restrict__ cursor, int* __restrict__ esrc) {
  int i = blockIdx.x * 256 + threadIdx.x;
  if (i < NE) {
    int pos = atomicAdd(&cursor[dst[i]], 1);
    esrc[pos] = src[i];
  } else if (i < ET) {
    int n = i - NE;
    int pos = atomicAdd(&cursor[n], 1);
    esrc[pos] = n;
  }
}

// ---------------- GEMM (h = X @ W) with fused alpha_src/alpha_dst epilogue ----------------
// X: NN x 128, W: 128 x M row-major, Hf: NN x M.
// M=128 -> HH=8 heads x 16 ch (each thread owns exactly one head's channels)
// M=64  -> HH=1 head  x 64 ch (shuffle-reduce over the 8 threads of a row)
template<int M, int HH>
__global__ __launch_bounds__(256) void k_gemm(const float* __restrict__ X, const float* __restrict__ W,
                                              const float* __restrict__ a_src, const float* __restrict__ a_dst,
                                              float* __restrict__ Hf, float* __restrict__ as_, float* __restrict__ ad_) {
  constexpr int CPT = (32 * M) / 256;   // cols per thread: 16 (M=128) / 8 (M=64)
  constexpr int TPR = M / CPT;          // threads per row: 8
  __shared__ float xs[32][128];
  __shared__ float ws[128 * M];
  int b = blockIdx.x, t = threadIdx.x;
  int row0 = b * 32;
  for (int i = t; i < 128 * M; i += 256) ws[i] = W[i];
  for (int i = t; i < 32 * 128; i += 256) {
    int r = i >> 7, c = i & 127;
    int gr = row0 + r;
    xs[r][c] = (gr < NN) ? X[gr * 128 + c] : 0.f;
  }
  __syncthreads();
  int r = t / TPR, c0 = (t % TPR) * CPT;
  float acc[CPT];
#pragma unroll
  for (int j = 0; j < CPT; j++) acc[j] = 0.f;
  for (int k = 0; k < 128; k++) {
    float xv = xs[r][k];
#pragma unroll
    for (int j = 0; j < CPT; j++) acc[j] += xv * ws[k * M + c0 + j];
  }
  // fused attention dots
  float s1 = 0.f, s2 = 0.f;
#pragma unroll
  for (int j = 0; j < CPT; j++) { s1 += acc[j] * a_src[c0 + j]; s2 += acc[j] * a_dst[c0 + j]; }
  if constexpr (HH == 1) {
#pragma unroll
    for (int off = 1; off < TPR; off <<= 1) { s1 += __shfl_xor(s1, off); s2 += __shfl_xor(s2, off); }
  }
  int gr = row0 + r;
  if (gr < NN) {
#pragma unroll
    for (int j = 0; j < CPT; j++) Hf[gr * M + c0 + j] = acc[j];
    if constexpr (HH == 1) {
      if ((t & (TPR - 1)) == 0) { as_[gr] = s1; ad_[gr] = s2; }
    } else {
      as_[gr * HH + (c0 >> 4)] = s1;   // c0>>4 == head index (CPT==16)
      ad_[gr * HH + (c0 >> 4)] = s2;
    }
  }
}

// ---------------- per-destination online-softmax aggregation + bias + ELU ----------------
// one thread per (node, 4-channel quad); fully independent threads, no atomics
template<int HH, int C>
__global__ __launch_bounds__(256) void k_aggregate(const float* __restrict__ Hf, const float* __restrict__ as_,
                                                   const float* __restrict__ ad_, const int* __restrict__ rowptr,
                                                   const int* __restrict__ esrc, const float* __restrict__ bias,
                                                   float* __restrict__ out) {
  constexpr int CT = HH * C;
  constexpr int Q = CT / 4;
  int g = blockIdx.x * 256 + threadIdx.x;
  if (g >= NN * Q) return;
  int node = g / Q;
  int q = g - node * Q;
  int c = q * 4;
  int hh = c / C;
  int i0 = rowptr[node], i1 = rowptr[node + 1];
  float ad = ad_[node * HH + hh];
  float m = -INFINITY, den = 0.f;
  float4 acc = make_float4(0.f, 0.f, 0.f, 0.f);
  for (int i = i0; i < i1; i++) {
    int s = esrc[i];
    float e = as_[s * HH + hh] + ad;
    e = e > 0.f ? e : 0.2f * e;                       // leaky_relu(0.2)
    float nm = fmaxf(m, e);
    float sc = __expf(m - nm);                        // exp(-inf)=0 handles first iter
    float p  = __expf(e - nm);
    float4 hv = *(const float4*)(Hf + s * CT + c);
    den = den * sc + p;
    acc.x = acc.x * sc + p * hv.x;
    acc.y = acc.y * sc + p * hv.y;
    acc.z = acc.z * sc + p * hv.z;
    acc.w = acc.w * sc + p * hv.w;
    m = nm;
  }
  float inv = 1.f / den;
  float4 o;
  o.x = acc.x * inv + bias[c + 0];
  o.y = acc.y * inv + bias[c + 1];
  o.z = acc.z * inv + bias[c + 2];
  o.w = acc.w * inv + bias[c + 3];
  o.x = o.x > 0.f ? o.x : __expf(o.x) - 1.f;          // ELU
  o.y = o.y > 0.f ? o.y : __expf(o.y) - 1.f;
  o.z = o.z > 0.f ? o.z : __expf(o.z) - 1.f;
  o.w = o.w > 0.f ? o.w : __expf(o.w) - 1.f;
  *(float4*)(out + node * CT + c) = o;
}

// ---------------- final 64 -> 2 linear ----------------
__global__ __launch_bounds__(256) void k_final(const float* __restrict__ H3, const float* __restrict__ Wout,
                                               const float* __restrict__ bout, float* __restrict__ out) {
  int i = blockIdx.x * 256 + threadIdx.x;
  if (i >= NN * 2) return;
  int n = i >> 1, c = i & 1;
  const float* hr = H3 + n * 64;
  float s = 0.f;
#pragma unroll
  for (int k = 0; k < 64; k++) s += hr[k] * Wout[k * 2 + c];
  out[i] = s + bout[c];
}

extern "C" void kernel_launch(void* const* d_in, const int* in_sizes, int n_in,
                              void* d_out, int out_size, void* d_ws, size_t ws_size,
                              hipStream_t stream) {
  const float* x    = (const float*)d_in[0];
  const int*   ei   = (const int*)d_in[1];
  const float* W1   = (const float*)d_in[2];
  const float* as1  = (const float*)d_in[3];
  const float* ad1  = (const float*)d_in[4];
  const float* b1   = (const float*)d_in[5];
  const float* W2   = (const float*)d_in[6];
  const float* as2  = (const float*)d_in[7];
  const float* ad2  = (const float*)d_in[8];
  const float* b2   = (const float*)d_in[9];
  const float* W3   = (const float*)d_in[10];
  const float* as3  = (const float*)d_in[11];
  const float* ad3  = (const float*)d_in[12];
  const float* b3   = (const float*)d_in[13];
  const float* Wout = (const float*)d_in[14];
  const float* bout = (const float*)d_in[15];
  const int* srcp = ei;
  const int* dstp = ei + NE;

  char* p = (char*)d_ws;
  auto alloc = [&](size_t bytes) { char* r = p; p += (bytes + 255) & ~size_t(255); return r; };
  int*   rowptr  = (int*)alloc((size_t)(NN + 1) * 4);
  int*   counts  = (int*)alloc((size_t)NN * 4);
  int*   cursor  = (int*)alloc((size_t)NN * 4);
  int*   partial = (int*)alloc((size_t)NN * 4);
  int*   blksum  = (int*)alloc(256 * 4);
  int*   esrc    = (int*)alloc((size_t)ET * 4);
  float* asb     = (float*)alloc((size_t)NN * 8 * 4);
  float* adb     = (float*)alloc((size_t)NN * 8 * 4);
  float* bufA    = (float*)alloc((size_t)NN * 128 * 4);
  float* bufB    = (float*)alloc((size_t)NN * 128 * 4);

  hipMemsetAsync(counts, 0, (size_t)NN * 4, stream);
  int gE = (ET + 255) / 256;
  int nb = (NN + 1023) / 1024;
  k_hist<<<gE, 256, 0, stream>>>(dstp, counts);
  k_scan1<<<nb, 256, 0, stream>>>(counts, partial, blksum);
  k_scan2<<<1, 256, 0, stream>>>(blksum, nb);
  k_scan3<<<(NN + 255) / 256, 256, 0, stream>>>(partial, blksum, counts, rowptr, cursor);
  k_scatter<<<gE, 256, 0, stream>>>(srcp, dstp, cursor, esrc);

  int gGemm = (NN + 31) / 32;
  // layer 1: 128 -> 8x16, concat, ELU
  k_gemm<128, 8><<<gGemm, 256, 0, stream>>>(x, W1, as1, ad1, bufA, asb, adb);
  k_aggregate<8, 16><<<(NN * 32 + 255) / 256, 256, 0, stream>>>(bufA, asb, adb, rowptr, esrc, b1, bufB);
  // layer 2
  k_gemm<128, 8><<<gGemm, 256, 0, stream>>>(bufB, W2, as2, ad2, bufA, asb, adb);
  k_aggregate<8, 16><<<(NN * 32 + 255) / 256, 256, 0, stream>>>(bufA, asb, adb, rowptr, esrc, b2, bufB);
  // layer 3: 128 -> 1x64, mean(=identity), ELU
  k_gemm<64, 1><<<gGemm, 256, 0, stream>>>(bufB, W3, as3, ad3, bufA, asb, adb);
  k_aggregate<1, 64><<<(NN * 16 + 255) / 256, 256, 0, stream>>>(bufA, asb, adb, rowptr, esrc, b3, bufB);
  // output head
  k_final<<<(NN * 2 + 255) / 256, 256, 0, stream>>>(bufB, Wout, bout, (float*)d_out);
}

// Round 2
// 610.044 us; speedup vs baseline: 1.5051x; 1.5051x over previous
//
#include <hip/hip_runtime.h>
#include <math.h>

#define NN 100000
#define NE 1600000
#define ET (NE + NN)

// ---------------- CSR build ----------------
// pass 1: histogram + record per-edge slot within its destination bucket
__global__ __launch_bounds__(256) void k_hist(const int* __restrict__ dst, int* __restrict__ counts,
                                              int* __restrict__ slots) {
  int i = blockIdx.x * 256 + threadIdx.x;
  if (i >= ET) return;
  int d = (i < NE) ? dst[i] : (i - NE);
  slots[i] = atomicAdd(&counts[d], 1);
}

__global__ __launch_bounds__(256) void k_scan1(const int* __restrict__ counts, int* __restrict__ partial,
                                               int* __restrict__ blksum) {
  __shared__ int lds[256];
  int b = blockIdx.x, t = threadIdx.x;
  int base = b * 1024 + t * 4;
  int v[4];
#pragma unroll
  for (int j = 0; j < 4; j++) v[j] = (base + j < NN) ? counts[base + j] : 0;
  int s = 0;
#pragma unroll
  for (int j = 0; j < 4; j++) { s += v[j]; v[j] = s; }   // inclusive within thread
  lds[t] = s; __syncthreads();
  int tot = s;
  for (int off = 1; off < 256; off <<= 1) {
    int u = 0; if (t >= off) u = lds[t - off];
    __syncthreads(); lds[t] += u; __syncthreads();
  }
  int pre = lds[t] - tot;
#pragma unroll
  for (int j = 0; j < 4; j++) if (base + j < NN) partial[base + j] = pre + v[j];
  if (t == 255) blksum[b] = lds[255];
}

__global__ __launch_bounds__(256) void k_scan2(int* __restrict__ blksum, int nb) {
  __shared__ int lds[256];
  int t = threadIdx.x;
  int v = (t < nb) ? blksum[t] : 0;
  lds[t] = v; __syncthreads();
  for (int off = 1; off < 256; off <<= 1) {
    int u = 0; if (t >= off) u = lds[t - off];
    __syncthreads(); lds[t] += u; __syncthreads();
  }
  if (t < nb) blksum[t] = lds[t] - v;   // exclusive block offsets
}

__global__ __launch_bounds__(256) void k_scan3(const int* __restrict__ partial, const int* __restrict__ blksum,
                                               int* __restrict__ rowptr) {
  int i = blockIdx.x * 256 + threadIdx.x;
  if (i >= NN) return;
  rowptr[i + 1] = partial[i] + blksum[i >> 10];
  if (i == 0) rowptr[0] = 0;
}

// pass 2: coalesced reads, one random 4B write per edge (no atomics)
__global__ __launch_bounds__(256) void k_scatter(const int* __restrict__ src, const int* __restrict__ dst,
                                                 const int* __restrict__ rowptr, const int* __restrict__ slots,
                                                 int* __restrict__ esrc) {
  int i = blockIdx.x * 256 + threadIdx.x;
  if (i >= ET) return;
  int d, s;
  if (i < NE) { d = dst[i]; s = src[i]; }
  else        { d = i - NE; s = i - NE; }
  esrc[rowptr[d] + slots[i]] = s;
}

// ---------------- register-tiled GEMM (h = X @ W) + fused alpha epilogue ----------------
// X: NN x 128 (row stride 128). W: 128 x M row-major. Hf: NN x M.
// Block: 64 rows x M cols, 256 threads, thread = 4 rows x (M/16) cols.
template<int M>
__global__ __launch_bounds__(256) void k_gemm(const float* __restrict__ X, const float* __restrict__ W,
                                              const float* __restrict__ a_src, const float* __restrict__ a_dst,
                                              float* __restrict__ Hf, float* __restrict__ as_, float* __restrict__ ad_) {
  constexpr int CPT = M / 16;          // cols per thread: 8 (M=128) / 4 (M=64)
  __shared__ float xs[64 * 36];        // x tile [64 rows][32 k] stride 36 (2-way banks = free)
  __shared__ float ws[32 * M];         // w tile [32 k][M cols]
  const int t = threadIdx.x;
  const int tx = t & 15, ty = t >> 4;
  const int row0 = blockIdx.x * 64;
  const int c0 = tx * CPT;
  float acc[4][CPT];
#pragma unroll
  for (int i = 0; i < 4; i++)
#pragma unroll
    for (int j = 0; j < CPT; j++) acc[i][j] = 0.f;

  for (int st = 0; st < 4; ++st) {
    const int k0 = st * 32;
    __syncthreads();
    // stage X tile: 64x32 floats = 512 float4, 2 per thread
#pragma unroll
    for (int j = 0; j < 2; ++j) {
      int flat = t + j * 256;
      int r = flat >> 3, c4 = (flat & 7) * 4;
      float4 v = make_float4(0.f, 0.f, 0.f, 0.f);
      if (row0 + r < NN) v = *(const float4*)(X + (size_t)(row0 + r) * 128 + k0 + c4);
      *(float4*)(xs + r * 36 + c4) = v;
    }
    // stage W tile: 32xM floats
#pragma unroll
    for (int j = 0; j < M / 32; ++j) {
      int flat = t + j * 256;
      int r = flat / (M / 4), c4 = (flat % (M / 4)) * 4;
      *(float4*)(ws + r * M + c4) = *(const float4*)(W + (size_t)(k0 + r) * M + c4);
    }
    __syncthreads();
#pragma unroll
    for (int kk = 0; kk < 32; kk += 4) {
      float4 xv[4];
#pragma unroll
      for (int i = 0; i < 4; ++i) xv[i] = *(const float4*)(xs + (ty * 4 + i) * 36 + kk);
#pragma unroll
      for (int j = 0; j < 4; ++j) {
#pragma unroll
        for (int cc = 0; cc < CPT; cc += 4) {
          float4 wv = *(const float4*)(ws + (kk + j) * M + c0 + cc);
#pragma unroll
          for (int i = 0; i < 4; ++i) {
            float xx = ((const float*)&xv[i])[j];
            acc[i][cc + 0] += xx * wv.x;
            acc[i][cc + 1] += xx * wv.y;
            acc[i][cc + 2] += xx * wv.z;
            acc[i][cc + 3] += xx * wv.w;
          }
        }
      }
    }
  }

  // fused attention dots: alpha_src/alpha_dst per (row, head)
  float s1[4], s2[4];
#pragma unroll
  for (int i = 0; i < 4; ++i) {
    float a = 0.f, b = 0.f;
#pragma unroll
    for (int j = 0; j < CPT; ++j) { a += acc[i][j] * a_src[c0 + j]; b += acc[i][j] * a_dst[c0 + j]; }
    s1[i] = a; s2[i] = b;
  }
  if constexpr (M == 128) {
    // head = 16 cols = 2 threads; reduce with lane partner tx^1
#pragma unroll
    for (int i = 0; i < 4; ++i) { s1[i] += __shfl_xor(s1[i], 1); s2[i] += __shfl_xor(s2[i], 1); }
  } else {
    // single head of 64 cols = 16 threads
#pragma unroll
    for (int off = 1; off < 16; off <<= 1)
#pragma unroll
      for (int i = 0; i < 4; ++i) { s1[i] += __shfl_xor(s1[i], off); s2[i] += __shfl_xor(s2[i], off); }
  }
#pragma unroll
  for (int i = 0; i < 4; ++i) {
    int r = row0 + ty * 4 + i;
    if (r < NN) {
#pragma unroll
      for (int cc = 0; cc < CPT; cc += 4)
        *(float4*)(Hf + (size_t)r * M + c0 + cc) = make_float4(acc[i][cc], acc[i][cc + 1], acc[i][cc + 2], acc[i][cc + 3]);
      if constexpr (M == 128) {
        if ((tx & 1) == 0) { as_[r * 8 + (tx >> 1)] = s1[i]; ad_[r * 8 + (tx >> 1)] = s2[i]; }
      } else {
        if (tx == 0) { as_[r] = s1[i]; ad_[r] = s2[i]; }
      }
    }
  }
}

// ---------------- per-destination online-softmax aggregation + bias + ELU ----------------
// one thread per (node, 4-channel quad); FINAL fuses the 64->2 output linear
template<int HH, int C, bool FINAL>
__global__ __launch_bounds__(256) void k_aggregate(const float* __restrict__ Hf, const float* __restrict__ as_,
                                                   const float* __restrict__ ad_, const int* __restrict__ rowptr,
                                                   const int* __restrict__ esrc, const float* __restrict__ bias,
                                                   const float* __restrict__ Wout, const float* __restrict__ bout,
                                                   float* __restrict__ out) {
  constexpr int CT = HH * C;
  constexpr int Q = CT / 4;
  int g = blockIdx.x * 256 + threadIdx.x;
  if (g >= NN * Q) return;
  int node = g / Q;
  int q = g - node * Q;
  int c = q * 4;
  int hh = c / C;
  int i0 = rowptr[node], i1 = rowptr[node + 1];
  float ad = ad_[node * HH + hh];
  float m = -INFINITY, den = 0.f;
  float4 acc = make_float4(0.f, 0.f, 0.f, 0.f);
  for (int i = i0; i < i1; i++) {
    int s = esrc[i];
    float e = as_[s * HH + hh] + ad;
    e = e > 0.f ? e : 0.2f * e;                       // leaky_relu(0.2)
    float nm = fmaxf(m, e);
    float sc = __expf(m - nm);                        // exp(-inf)=0 handles first iter
    float p  = __expf(e - nm);
    float4 hv = *(const float4*)(Hf + (size_t)s * CT + c);
    den = den * sc + p;
    acc.x = acc.x * sc + p * hv.x;
    acc.y = acc.y * sc + p * hv.y;
    acc.z = acc.z * sc + p * hv.z;
    acc.w = acc.w * sc + p * hv.w;
    m = nm;
  }
  float inv = 1.f / den;
  float4 o;
  o.x = acc.x * inv + bias[c + 0];
  o.y = acc.y * inv + bias[c + 1];
  o.z = acc.z * inv + bias[c + 2];
  o.w = acc.w * inv + bias[c + 3];
  o.x = o.x > 0.f ? o.x : __expf(o.x) - 1.f;          // ELU
  o.y = o.y > 0.f ? o.y : __expf(o.y) - 1.f;
  o.z = o.z > 0.f ? o.z : __expf(o.z) - 1.f;
  o.w = o.w > 0.f ? o.w : __expf(o.w) - 1.f;
  if constexpr (!FINAL) {
    *(float4*)(out + (size_t)node * CT + c) = o;
  } else {
    // fused out = elu(h3) @ Wout + bout ; reduce over the node's 16 lanes
    float p0 = o.x * Wout[(c + 0) * 2 + 0] + o.y * Wout[(c + 1) * 2 + 0]
             + o.z * Wout[(c + 2) * 2 + 0] + o.w * Wout[(c + 3) * 2 + 0];
    float p1 = o.x * Wout[(c + 0) * 2 + 1] + o.y * Wout[(c + 1) * 2 + 1]
             + o.z * Wout[(c + 2) * 2 + 1] + o.w * Wout[(c + 3) * 2 + 1];
#pragma unroll
    for (int off = 1; off < 16; off <<= 1) { p0 += __shfl_xor(p0, off); p1 += __shfl_xor(p1, off); }
    if (q == 0) { out[node * 2 + 0] = p0 + bout[0]; out[node * 2 + 1] = p1 + bout[1]; }
  }
}

extern "C" void kernel_launch(void* const* d_in, const int* in_sizes, int n_in,
                              void* d_out, int out_size, void* d_ws, size_t ws_size,
                              hipStream_t stream) {
  const float* x    = (const float*)d_in[0];
  const int*   ei   = (const int*)d_in[1];
  const float* W1   = (const float*)d_in[2];
  const float* as1  = (const float*)d_in[3];
  const float* ad1  = (const float*)d_in[4];
  const float* b1   = (const float*)d_in[5];
  const float* W2   = (const float*)d_in[6];
  const float* as2  = (const float*)d_in[7];
  const float* ad2  = (const float*)d_in[8];
  const float* b2   = (const float*)d_in[9];
  const float* W3   = (const float*)d_in[10];
  const float* as3  = (const float*)d_in[11];
  const float* ad3  = (const float*)d_in[12];
  const float* b3   = (const float*)d_in[13];
  const float* Wout = (const float*)d_in[14];
  const float* bout = (const float*)d_in[15];
  const int* srcp = ei;
  const int* dstp = ei + NE;

  char* p = (char*)d_ws;
  auto alloc = [&](size_t bytes) { char* r = p; p += (bytes + 255) & ~size_t(255); return r; };
  int*   rowptr  = (int*)alloc((size_t)(NN + 1) * 4);
  int*   counts  = (int*)alloc((size_t)NN * 4);
  int*   partial = (int*)alloc((size_t)NN * 4);
  int*   blksum  = (int*)alloc(256 * 4);
  int*   esrc    = (int*)alloc((size_t)ET * 4);
  int*   slots   = (int*)alloc((size_t)ET * 4);
  float* asb     = (float*)alloc((size_t)NN * 8 * 4);
  float* adb     = (float*)alloc((size_t)NN * 8 * 4);
  float* bufA    = (float*)alloc((size_t)NN * 128 * 4);
  float* bufB    = (float*)alloc((size_t)NN * 128 * 4);

  hipMemsetAsync(counts, 0, (size_t)NN * 4, stream);
  int gE = (ET + 255) / 256;
  int nb = (NN + 1023) / 1024;
  k_hist<<<gE, 256, 0, stream>>>(dstp, counts, slots);
  k_scan1<<<nb, 256, 0, stream>>>(counts, partial, blksum);
  k_scan2<<<1, 256, 0, stream>>>(blksum, nb);
  k_scan3<<<(NN + 255) / 256, 256, 0, stream>>>(partial, blksum, rowptr);
  k_scatter<<<gE, 256, 0, stream>>>(srcp, dstp, rowptr, slots, esrc);

  int gGemm = (NN + 63) / 64;
  // layer 1: 128 -> 8x16, concat, ELU
  k_gemm<128><<<gGemm, 256, 0, stream>>>(x, W1, as1, ad1, bufA, asb, adb);
  k_aggregate<8, 16, false><<<(NN * 32 + 255) / 256, 256, 0, stream>>>(bufA, asb, adb, rowptr, esrc, b1, nullptr, nullptr, bufB);
  // layer 2
  k_gemm<128><<<gGemm, 256, 0, stream>>>(bufB, W2, as2, ad2, bufA, asb, adb);
  k_aggregate<8, 16, false><<<(NN * 32 + 255) / 256, 256, 0, stream>>>(bufA, asb, adb, rowptr, esrc, b2, nullptr, nullptr, bufB);
  // layer 3: 128 -> 1x64, mean(=identity), ELU, fused 64->2 output linear
  k_gemm<64><<<gGemm, 256, 0, stream>>>(bufB, W3, as3, ad3, bufA, asb, adb);
  k_aggregate<1, 64, true><<<(NN * 16 + 255) / 256, 256, 0, stream>>>(bufA, asb, adb, rowptr, esrc, b3, Wout, bout, (float*)d_out);
}

// Round 3
// 550.681 us; speedup vs baseline: 1.6674x; 1.1078x over previous
//
#include <hip/hip_runtime.h>
#include <math.h>

#define NN 100000
#define NE 1600000
#define ET (NE + NN)

__device__ inline unsigned short f2bf(float f) {            // RNE float->bf16
  union { float f; unsigned u; } v; v.f = f;
  unsigned r = v.u + 0x7fffu + ((v.u >> 16) & 1u);
  return (unsigned short)(r >> 16);
}
__device__ inline float bflo(unsigned u) { union { unsigned u; float f; } v; v.u = u << 16; return v.f; }
__device__ inline float bfhi(unsigned u) { union { unsigned u; float f; } v; v.u = u & 0xffff0000u; return v.f; }

// ---------------- CSR build ----------------
// pass 1: histogram + record per-edge slot within its destination bucket
__global__ __launch_bounds__(256) void k_hist(const int* __restrict__ dst, int* __restrict__ counts,
                                              int* __restrict__ slots) {
  int i = blockIdx.x * 256 + threadIdx.x;
  if (i >= ET) return;
  int d = (i < NE) ? dst[i] : (i - NE);
  slots[i] = atomicAdd(&counts[d], 1);
}

__global__ __launch_bounds__(256) void k_scan1(const int* __restrict__ counts, int* __restrict__ partial,
                                               int* __restrict__ blksum) {
  __shared__ int lds[256];
  int b = blockIdx.x, t = threadIdx.x;
  int base = b * 1024 + t * 4;
  int v[4];
#pragma unroll
  for (int j = 0; j < 4; j++) v[j] = (base + j < NN) ? counts[base + j] : 0;
  int s = 0;
#pragma unroll
  for (int j = 0; j < 4; j++) { s += v[j]; v[j] = s; }   // inclusive within thread
  lds[t] = s; __syncthreads();
  int tot = s;
  for (int off = 1; off < 256; off <<= 1) {
    int u = 0; if (t >= off) u = lds[t - off];
    __syncthreads(); lds[t] += u; __syncthreads();
  }
  int pre = lds[t] - tot;
#pragma unroll
  for (int j = 0; j < 4; j++) if (base + j < NN) partial[base + j] = pre + v[j];
  if (t == 255) blksum[b] = lds[255];
}

__global__ __launch_bounds__(256) void k_scan2(int* __restrict__ blksum, int nb) {
  __shared__ int lds[256];
  int t = threadIdx.x;
  int v = (t < nb) ? blksum[t] : 0;
  lds[t] = v; __syncthreads();
  for (int off = 1; off < 256; off <<= 1) {
    int u = 0; if (t >= off) u = lds[t - off];
    __syncthreads(); lds[t] += u; __syncthreads();
  }
  if (t < nb) blksum[t] = lds[t] - v;   // exclusive block offsets
}

__global__ __launch_bounds__(256) void k_scan3(const int* __restrict__ partial, const int* __restrict__ blksum,
                                               int* __restrict__ rowptr) {
  int i = blockIdx.x * 256 + threadIdx.x;
  if (i >= NN) return;
  rowptr[i + 1] = partial[i] + blksum[i >> 10];
  if (i == 0) rowptr[0] = 0;
}

// pass 2: coalesced reads, one random 4B write per edge (no atomics)
__global__ __launch_bounds__(256) void k_scatter(const int* __restrict__ src, const int* __restrict__ dst,
                                                 const int* __restrict__ rowptr, const int* __restrict__ slots,
                                                 int* __restrict__ esrc) {
  int i = blockIdx.x * 256 + threadIdx.x;
  if (i >= ET) return;
  int d, s;
  if (i < NE) { d = dst[i]; s = src[i]; }
  else        { d = i - NE; s = i - NE; }
  esrc[rowptr[d] + slots[i]] = s;
}

// ---------------- register-tiled GEMM (h = X @ W) + fused alpha epilogue ----------------
// X: NN x 128 fp32. W: 128 x M row-major fp32. Hf: NN x M bf16 (gather table).
// Block: 64 rows x M cols, 256 threads, thread = 4 rows x (M/16) cols.
template<int M>
__global__ __launch_bounds__(256) void k_gemm(const float* __restrict__ X, const float* __restrict__ W,
                                              const float* __restrict__ a_src, const float* __restrict__ a_dst,
                                              unsigned short* __restrict__ Hf, float* __restrict__ as_, float* __restrict__ ad_) {
  constexpr int CPT = M / 16;          // cols per thread: 8 (M=128) / 4 (M=64)
  __shared__ float xs[64 * 36];        // x tile [64 rows][32 k] stride 36 (2-way banks = free)
  __shared__ float ws[32 * M];         // w tile [32 k][M cols]
  const int t = threadIdx.x;
  const int tx = t & 15, ty = t >> 4;
  const int row0 = blockIdx.x * 64;
  const int c0 = tx * CPT;
  float acc[4][CPT];
#pragma unroll
  for (int i = 0; i < 4; i++)
#pragma unroll
    for (int j = 0; j < CPT; j++) acc[i][j] = 0.f;

  for (int st = 0; st < 4; ++st) {
    const int k0 = st * 32;
    __syncthreads();
    // stage X tile: 64x32 floats = 512 float4, 2 per thread
#pragma unroll
    for (int j = 0; j < 2; ++j) {
      int flat = t + j * 256;
      int r = flat >> 3, c4 = (flat & 7) * 4;
      float4 v = make_float4(0.f, 0.f, 0.f, 0.f);
      if (row0 + r < NN) v = *(const float4*)(X + (size_t)(row0 + r) * 128 + k0 + c4);
      *(float4*)(xs + r * 36 + c4) = v;
    }
    // stage W tile: 32xM floats
#pragma unroll
    for (int j = 0; j < M / 32; ++j) {
      int flat = t + j * 256;
      int r = flat / (M / 4), c4 = (flat % (M / 4)) * 4;
      *(float4*)(ws + r * M + c4) = *(const float4*)(W + (size_t)(k0 + r) * M + c4);
    }
    __syncthreads();
#pragma unroll
    for (int kk = 0; kk < 32; kk += 4) {
      float4 xv[4];
#pragma unroll
      for (int i = 0; i < 4; ++i) xv[i] = *(const float4*)(xs + (ty * 4 + i) * 36 + kk);
#pragma unroll
      for (int j = 0; j < 4; ++j) {
#pragma unroll
        for (int cc = 0; cc < CPT; cc += 4) {
          float4 wv = *(const float4*)(ws + (kk + j) * M + c0 + cc);
#pragma unroll
          for (int i = 0; i < 4; ++i) {
            float xx = ((const float*)&xv[i])[j];
            acc[i][cc + 0] += xx * wv.x;
            acc[i][cc + 1] += xx * wv.y;
            acc[i][cc + 2] += xx * wv.z;
            acc[i][cc + 3] += xx * wv.w;
          }
        }
      }
    }
  }

  // fused attention dots: alpha_src/alpha_dst per (row, head)
  float s1[4], s2[4];
#pragma unroll
  for (int i = 0; i < 4; ++i) {
    float a = 0.f, b = 0.f;
#pragma unroll
    for (int j = 0; j < CPT; ++j) { a += acc[i][j] * a_src[c0 + j]; b += acc[i][j] * a_dst[c0 + j]; }
    s1[i] = a; s2[i] = b;
  }
  if constexpr (M == 128) {
    // head = 16 cols = 2 threads; reduce with lane partner tx^1
#pragma unroll
    for (int i = 0; i < 4; ++i) { s1[i] += __shfl_xor(s1[i], 1); s2[i] += __shfl_xor(s2[i], 1); }
  } else {
    // single head of 64 cols = 16 threads
#pragma unroll
    for (int off = 1; off < 16; off <<= 1)
#pragma unroll
      for (int i = 0; i < 4; ++i) { s1[i] += __shfl_xor(s1[i], off); s2[i] += __shfl_xor(s2[i], off); }
  }
#pragma unroll
  for (int i = 0; i < 4; ++i) {
    int r = row0 + ty * 4 + i;
    if (r < NN) {
      if constexpr (M == 128) {
        uint4 pk;
        pk.x = (unsigned)f2bf(acc[i][0]) | ((unsigned)f2bf(acc[i][1]) << 16);
        pk.y = (unsigned)f2bf(acc[i][2]) | ((unsigned)f2bf(acc[i][3]) << 16);
        pk.z = (unsigned)f2bf(acc[i][4]) | ((unsigned)f2bf(acc[i][5]) << 16);
        pk.w = (unsigned)f2bf(acc[i][6]) | ((unsigned)f2bf(acc[i][7]) << 16);
        *(uint4*)(Hf + (size_t)r * M + c0) = pk;
        if ((tx & 1) == 0) { as_[r * 8 + (tx >> 1)] = s1[i]; ad_[r * 8 + (tx >> 1)] = s2[i]; }
      } else {
        uint2 pk;
        pk.x = (unsigned)f2bf(acc[i][0]) | ((unsigned)f2bf(acc[i][1]) << 16);
        pk.y = (unsigned)f2bf(acc[i][2]) | ((unsigned)f2bf(acc[i][3]) << 16);
        *(uint2*)(Hf + (size_t)r * M + c0) = pk;
        if (tx == 0) { as_[r] = s1[i]; ad_[r] = s2[i]; }
      }
    }
  }
}

// ---------------- per-destination online-softmax aggregation + bias + ELU ----------------
// one thread per (node, 4-channel quad); gathers bf16 h rows; FINAL fuses the 64->2 linear
template<int HH, int C, bool FINAL>
__global__ __launch_bounds__(256) void k_aggregate(const unsigned short* __restrict__ Hf, const float* __restrict__ as_,
                                                   const float* __restrict__ ad_, const int* __restrict__ rowptr,
                                                   const int* __restrict__ esrc, const float* __restrict__ bias,
                                                   const float* __restrict__ Wout, const float* __restrict__ bout,
                                                   float* __restrict__ out) {
  constexpr int CT = HH * C;
  constexpr int Q = CT / 4;
  int g = blockIdx.x * 256 + threadIdx.x;
  if (g >= NN * Q) return;
  int node = g / Q;
  int q = g - node * Q;
  int c = q * 4;
  int hh = c / C;
  int i0 = rowptr[node], i1 = rowptr[node + 1];
  float ad = ad_[node * HH + hh];
  float m = -INFINITY, den = 0.f;
  float4 acc = make_float4(0.f, 0.f, 0.f, 0.f);
  for (int i = i0; i < i1; i++) {
    int s = esrc[i];
    float e = as_[s * HH + hh] + ad;
    e = e > 0.f ? e : 0.2f * e;                       // leaky_relu(0.2)
    float nm = fmaxf(m, e);
    float sc = __expf(m - nm);                        // exp(-inf)=0 handles first iter
    float p  = __expf(e - nm);
    uint2 hr = *(const uint2*)(Hf + (size_t)s * CT + c);
    den = den * sc + p;
    acc.x = acc.x * sc + p * bflo(hr.x);
    acc.y = acc.y * sc + p * bfhi(hr.x);
    acc.z = acc.z * sc + p * bflo(hr.y);
    acc.w = acc.w * sc + p * bfhi(hr.y);
    m = nm;
  }
  float inv = 1.f / den;
  float4 o;
  o.x = acc.x * inv + bias[c + 0];
  o.y = acc.y * inv + bias[c + 1];
  o.z = acc.z * inv + bias[c + 2];
  o.w = acc.w * inv + bias[c + 3];
  o.x = o.x > 0.f ? o.x : __expf(o.x) - 1.f;          // ELU
  o.y = o.y > 0.f ? o.y : __expf(o.y) - 1.f;
  o.z = o.z > 0.f ? o.z : __expf(o.z) - 1.f;
  o.w = o.w > 0.f ? o.w : __expf(o.w) - 1.f;
  if constexpr (!FINAL) {
    *(float4*)(out + (size_t)node * CT + c) = o;
  } else {
    // fused out = elu(h3) @ Wout + bout ; reduce over the node's 16 lanes
    float p0 = o.x * Wout[(c + 0) * 2 + 0] + o.y * Wout[(c + 1) * 2 + 0]
             + o.z * Wout[(c + 2) * 2 + 0] + o.w * Wout[(c + 3) * 2 + 0];
    float p1 = o.x * Wout[(c + 0) * 2 + 1] + o.y * Wout[(c + 1) * 2 + 1]
             + o.z * Wout[(c + 2) * 2 + 1] + o.w * Wout[(c + 3) * 2 + 1];
#pragma unroll
    for (int off = 1; off < 16; off <<= 1) { p0 += __shfl_xor(p0, off); p1 += __shfl_xor(p1, off); }
    if (q == 0) { out[node * 2 + 0] = p0 + bout[0]; out[node * 2 + 1] = p1 + bout[1]; }
  }
}

extern "C" void kernel_launch(void* const* d_in, const int* in_sizes, int n_in,
                              void* d_out, int out_size, void* d_ws, size_t ws_size,
                              hipStream_t stream) {
  const float* x    = (const float*)d_in[0];
  const int*   ei   = (const int*)d_in[1];
  const float* W1   = (const float*)d_in[2];
  const float* as1  = (const float*)d_in[3];
  const float* ad1  = (const float*)d_in[4];
  const float* b1   = (const float*)d_in[5];
  const float* W2   = (const float*)d_in[6];
  const float* as2  = (const float*)d_in[7];
  const float* ad2  = (const float*)d_in[8];
  const float* b2   = (const float*)d_in[9];
  const float* W3   = (const float*)d_in[10];
  const float* as3  = (const float*)d_in[11];
  const float* ad3  = (const float*)d_in[12];
  const float* b3   = (const float*)d_in[13];
  const float* Wout = (const float*)d_in[14];
  const float* bout = (const float*)d_in[15];
  const int* srcp = ei;
  const int* dstp = ei + NE;

  char* p = (char*)d_ws;
  auto alloc = [&](size_t bytes) { char* r = p; p += (bytes + 255) & ~size_t(255); return r; };
  int*            rowptr  = (int*)alloc((size_t)(NN + 1) * 4);
  int*            counts  = (int*)alloc((size_t)NN * 4);
  int*            partial = (int*)alloc((size_t)NN * 4);
  int*            blksum  = (int*)alloc(256 * 4);
  int*            esrc    = (int*)alloc((size_t)ET * 4);
  int*            slots   = (int*)alloc((size_t)ET * 4);
  float*          asb     = (float*)alloc((size_t)NN * 8 * 4);
  float*          adb     = (float*)alloc((size_t)NN * 8 * 4);
  unsigned short* hfb     = (unsigned short*)alloc((size_t)NN * 128 * 2);   // bf16 gather table
  float*          bufB    = (float*)alloc((size_t)NN * 128 * 4);            // fp32 X for next GEMM

  hipMemsetAsync(counts, 0, (size_t)NN * 4, stream);
  int gE = (ET + 255) / 256;
  int nb = (NN + 1023) / 1024;
  k_hist<<<gE, 256, 0, stream>>>(dstp, counts, slots);
  k_scan1<<<nb, 256, 0, stream>>>(counts, partial, blksum);
  k_scan2<<<1, 256, 0, stream>>>(blksum, nb);
  k_scan3<<<(NN + 255) / 256, 256, 0, stream>>>(partial, blksum, rowptr);
  k_scatter<<<gE, 256, 0, stream>>>(srcp, dstp, rowptr, slots, esrc);

  int gGemm = (NN + 63) / 64;
  // layer 1: 128 -> 8x16, concat, ELU
  k_gemm<128><<<gGemm, 256, 0, stream>>>(x, W1, as1, ad1, hfb, asb, adb);
  k_aggregate<8, 16, false><<<(NN * 32 + 255) / 256, 256, 0, stream>>>(hfb, asb, adb, rowptr, esrc, b1, nullptr, nullptr, bufB);
  // layer 2
  k_gemm<128><<<gGemm, 256, 0, stream>>>(bufB, W2, as2, ad2, hfb, asb, adb);
  k_aggregate<8, 16, false><<<(NN * 32 + 255) / 256, 256, 0, stream>>>(hfb, asb, adb, rowptr, esrc, b2, nullptr, nullptr, bufB);
  // layer 3: 128 -> 1x64, mean(=identity), ELU, fused 64->2 output linear
  k_gemm<64><<<gGemm, 256, 0, stream>>>(bufB, W3, as3, ad3, hfb, asb, adb);
  k_aggregate<1, 64, true><<<(NN * 16 + 255) / 256, 256, 0, stream>>>(hfb, asb, adb, rowptr, esrc, b3, Wout, bout, (float*)d_out);
}